// Round 5
// baseline (30.430 us; speedup 1.0000x reference)
//
#include <hip/hip_runtime.h>
#include <hip/hip_bf16.h>
#include <cmath>

// Problem constants (fixed by the reference): B=8, S=4096, D=768, N=4.
#define DDIM 768
#define NLIN 4
#define RPW  4          // rows per wave
#define BLOCK 64        // ONE wave per block: finest scheduling granularity
#define LOG2E 1.4426950408889634f

typedef float f32x4 __attribute__((ext_vector_type(4)));

#if __has_builtin(__builtin_amdgcn_exp2f)
#define EXP2(x) __builtin_amdgcn_exp2f(x)
#else
#define EXP2(x) exp2f(x)
#endif
#if __has_builtin(__builtin_amdgcn_logf)
#define LOG2(x) __builtin_amdgcn_logf(x)
#else
#define LOG2(x) log2f(x)
#endif
#if __has_builtin(__builtin_amdgcn_rcpf)
#define RCP(x) __builtin_amdgcn_rcpf(x)
#else
#define RCP(x) (1.0f / (x))
#endif

__global__ __launch_bounds__(BLOCK) void ScaleNumEmbed_25726854103624_kernel(
    const float* __restrict__ embeds,   // [rows, D]
    const float* __restrict__ numbers,  // [rows]
    const int*   __restrict__ isnum,    // [rows] 0/1
    const float* __restrict__ W,        // [N, D]
    const float* __restrict__ bias,     // [N, D]
    float* __restrict__ out,            // [rows, D]
    int rows)
{
    const int lane = threadIdx.x & 63;
    const int base = blockIdx.x * RPW;
    if (base >= rows) return;

    // Per-row scalars (wave-uniform values -> s_loads).
    int   isn[RPW];
    float g[RPW];
#pragma unroll
    for (int r = 0; r < RPW; ++r) isn[r] = isnum[base + r];
#pragma unroll
    for (int r = 0; r < RPW; ++r) {
        // ln(num)*log2(e) == log2(num): one native v_log_f32 per row.
        g[r] = LOG2(numbers[base + r]);   // unused for copy rows
    }

    // Issue ALL embeds loads up front, branch-free (no control dependence).
    // Number rows read a dummy L1-hot window (W) instead of touching HBM.
    f32x4 v[RPW][3];
#pragma unroll
    for (int r = 0; r < RPW; ++r) {
        const f32x4* src = isn[r]
            ? reinterpret_cast<const f32x4*>(W)
            : reinterpret_cast<const f32x4*>(embeds + (size_t)(base + r) * DDIM);
#pragma unroll
        for (int k = 0; k < 3; ++k) {
            v[r][k] = src[lane + 64 * k];
        }
    }

#pragma unroll
    for (int k = 0; k < 3; ++k) {
        const int d0 = (lane + 64 * k) * 4;
        f32x4 wv[NLIN], b2[NLIN];
#pragma unroll
        for (int n = 0; n < NLIN; ++n) {
            wv[n] = *reinterpret_cast<const f32x4*>(W + n * DDIM + d0);
            const f32x4 bv = *reinterpret_cast<const f32x4*>(bias + n * DDIM + d0);
            b2[n] = bv * LOG2E;   // pre-scale bias into log2 domain
        }
#pragma unroll
        for (int r = 0; r < RPW; ++r) {
            f32x4 o;
            if (isn[r]) {   // wave-uniform branch: compute only number rows
                f32x4 acc = {0.0f, 0.0f, 0.0f, 0.0f};
#pragma unroll
                for (int n = 0; n < NLIN; ++n) {
                    // sigmoid(f*w+b) = rcp(1 + 2^(-(log2(num)*w + b*log2e)))
                    acc.x += RCP(1.0f + EXP2(-fmaf(g[r], wv[n].x, b2[n].x)));
                    acc.y += RCP(1.0f + EXP2(-fmaf(g[r], wv[n].y, b2[n].y)));
                    acc.z += RCP(1.0f + EXP2(-fmaf(g[r], wv[n].z, b2[n].z)));
                    acc.w += RCP(1.0f + EXP2(-fmaf(g[r], wv[n].w, b2[n].w)));
                }
                o = acc;
            } else {
                o = v[r][k];
            }
            f32x4* dst = reinterpret_cast<f32x4*>(out + (size_t)(base + r) * DDIM);
            dst[lane + 64 * k] = o;   // plain store: L3 absorbs the write stream
        }
    }
}

extern "C" void kernel_launch(void* const* d_in, const int* in_sizes, int n_in,
                              void* d_out, int out_size, void* d_ws, size_t ws_size,
                              hipStream_t stream) {
    const float* embeds  = (const float*)d_in[0];
    const float* numbers = (const float*)d_in[1];
    const int*   isnum   = (const int*)d_in[2];
    const float* W       = (const float*)d_in[3];
    const float* bias    = (const float*)d_in[4];
    float*       out     = (float*)d_out;

    const int rows = in_sizes[1];                 // B*S = 32768
    const int grid = (rows + RPW - 1) / RPW;      // 8192 one-wave blocks

    ScaleNumEmbed_25726854103624_kernel<<<grid, BLOCK, 0, stream>>>(
        embeds, numbers, isnum, W, bias, out, rows);
}

// Round 6
// 29.786 us; speedup vs baseline: 1.0216x; 1.0216x over previous
//
#include <hip/hip_runtime.h>
#include <hip/hip_bf16.h>
#include <cmath>

// Problem constants (fixed by the reference): B=8, S=4096, D=768, N=4.
#define DDIM 768
#define NLIN 4
#define RPW  4          // rows per wave
#define BLOCK 256       // 4 waves/block (R4 config; R5 showed block size is neutral)
#define LOG2E 1.4426950408889634f

typedef float f32x4 __attribute__((ext_vector_type(4)));

#if __has_builtin(__builtin_amdgcn_exp2f)
#define EXP2(x) __builtin_amdgcn_exp2f(x)
#else
#define EXP2(x) exp2f(x)
#endif
#if __has_builtin(__builtin_amdgcn_logf)
#define LOG2(x) __builtin_amdgcn_logf(x)
#else
#define LOG2(x) log2f(x)
#endif
#if __has_builtin(__builtin_amdgcn_rcpf)
#define RCP(x) __builtin_amdgcn_rcpf(x)
#else
#define RCP(x) (1.0f / (x))
#endif

__global__ __launch_bounds__(BLOCK) void ScaleNumEmbed_25726854103624_kernel(
    const float* __restrict__ embeds,   // [rows, D]
    const float* __restrict__ numbers,  // [rows]
    const int*   __restrict__ isnum,    // [rows] 0/1
    const float* __restrict__ W,        // [N, D]
    const float* __restrict__ bias,     // [N, D]
    float* __restrict__ out,            // [rows, D]
    int rows)
{
    const int lane = threadIdx.x & 63;
    const int wid  = (int)((blockIdx.x * blockDim.x + threadIdx.x) >> 6);
    const int base = wid * RPW;
    if (base >= rows) return;

    // Per-row scalars (wave-uniform values -> s_loads).
    int   isn[RPW];
    float g[RPW];
#pragma unroll
    for (int r = 0; r < RPW; ++r) isn[r] = isnum[base + r];
#pragma unroll
    for (int r = 0; r < RPW; ++r) {
        // ln(num)*log2(e) == log2(num): one native v_log_f32 per row.
        g[r] = LOG2(numbers[base + r]);   // unused for copy rows
    }

    // Issue ALL embeds loads up front, branch-free (no control dependence).
    // Number rows read a dummy L1-hot window (W) instead of touching HBM.
    // PLAIN loads: keep embeds L3-resident across graph replays.
    f32x4 v[RPW][3];
#pragma unroll
    for (int r = 0; r < RPW; ++r) {
        const f32x4* src = isn[r]
            ? reinterpret_cast<const f32x4*>(W)
            : reinterpret_cast<const f32x4*>(embeds + (size_t)(base + r) * DDIM);
#pragma unroll
        for (int k = 0; k < 3; ++k) {
            v[r][k] = src[lane + 64 * k];
        }
    }

#pragma unroll
    for (int k = 0; k < 3; ++k) {
        const int d0 = (lane + 64 * k) * 4;
        f32x4 wv[NLIN], b2[NLIN];
#pragma unroll
        for (int n = 0; n < NLIN; ++n) {
            wv[n] = *reinterpret_cast<const f32x4*>(W + n * DDIM + d0);
            const f32x4 bv = *reinterpret_cast<const f32x4*>(bias + n * DDIM + d0);
            b2[n] = bv * LOG2E;   // pre-scale bias into log2 domain
        }
#pragma unroll
        for (int r = 0; r < RPW; ++r) {
            f32x4 o;
            if (isn[r]) {   // wave-uniform branch: compute only number rows
                f32x4 acc = {0.0f, 0.0f, 0.0f, 0.0f};
#pragma unroll
                for (int n = 0; n < NLIN; ++n) {
                    // sigmoid(f*w+b) = rcp(1 + 2^(-(log2(num)*w + b*log2e)))
                    acc.x += RCP(1.0f + EXP2(-fmaf(g[r], wv[n].x, b2[n].x)));
                    acc.y += RCP(1.0f + EXP2(-fmaf(g[r], wv[n].y, b2[n].y)));
                    acc.z += RCP(1.0f + EXP2(-fmaf(g[r], wv[n].z, b2[n].z)));
                    acc.w += RCP(1.0f + EXP2(-fmaf(g[r], wv[n].w, b2[n].w)));
                }
                o = acc;
            } else {
                o = v[r][k];
            }
            f32x4* dst = reinterpret_cast<f32x4*>(out + (size_t)(base + r) * DDIM);
            // NT store: out is write-once, never re-read in the timed loop.
            // Keeps the 100 MB write stream out of L3 so embeds stays resident.
            __builtin_nontemporal_store(o, dst + lane + 64 * k);
        }
    }
}

extern "C" void kernel_launch(void* const* d_in, const int* in_sizes, int n_in,
                              void* d_out, int out_size, void* d_ws, size_t ws_size,
                              hipStream_t stream) {
    const float* embeds  = (const float*)d_in[0];
    const float* numbers = (const float*)d_in[1];
    const int*   isnum   = (const int*)d_in[2];
    const float* W       = (const float*)d_in[3];
    const float* bias    = (const float*)d_in[4];
    float*       out     = (float*)d_out;

    const int rows  = in_sizes[1];                 // B*S = 32768
    const int waves = (rows + RPW - 1) / RPW;      // 8192
    const int grid  = (waves + (BLOCK / 64) - 1) / (BLOCK / 64);  // 2048 blocks

    ScaleNumEmbed_25726854103624_kernel<<<grid, BLOCK, 0, stream>>>(
        embeds, numbers, isnum, W, bias, out, rows);
}

// Round 7
// 29.713 us; speedup vs baseline: 1.0241x; 1.0024x over previous
//
#include <hip/hip_runtime.h>
#include <hip/hip_bf16.h>
#include <cmath>

// Problem constants (fixed by the reference): B=8, S=4096, D=768, N=4.
#define DDIM 768
#define NLIN 4
#define RPW  4          // rows per wave
#define BLOCK 256       // 4 waves/block
#define LOG2E 1.4426950408889634f

typedef float f32x4 __attribute__((ext_vector_type(4)));

#if __has_builtin(__builtin_amdgcn_exp2f)
#define EXP2(x) __builtin_amdgcn_exp2f(x)
#else
#define EXP2(x) exp2f(x)
#endif
#if __has_builtin(__builtin_amdgcn_logf)
#define LOG2(x) __builtin_amdgcn_logf(x)
#else
#define LOG2(x) log2f(x)
#endif
#if __has_builtin(__builtin_amdgcn_rcpf)
#define RCP(x) __builtin_amdgcn_rcpf(x)
#else
#define RCP(x) (1.0f / (x))
#endif

__global__ __launch_bounds__(BLOCK) void ScaleNumEmbed_25726854103624_kernel(
    const float* __restrict__ embeds,   // [rows, D]
    const float* __restrict__ numbers,  // [rows]
    const int*   __restrict__ isnum,    // [rows] 0/1
    const float* __restrict__ W,        // [N, D]
    const float* __restrict__ bias,     // [N, D]
    float* __restrict__ out,            // [rows, D]
    int rows)
{
    const int lane = threadIdx.x & 63;
    const int wid  = (int)((blockIdx.x * blockDim.x + threadIdx.x) >> 6);
    const int base = wid * RPW;
    if (base >= rows) return;

    // Per-row scalars (wave-uniform values -> s_loads).
    int   isn[RPW];
    float g[RPW];
#pragma unroll
    for (int r = 0; r < RPW; ++r) isn[r] = isnum[base + r];
#pragma unroll
    for (int r = 0; r < RPW; ++r) {
        // ln(num)*log2(e) == log2(num): one native v_log_f32 per row.
        g[r] = LOG2(numbers[base + r]);   // unused for copy rows
    }

    // Embeds loads: ONLY for copy rows, via wave-uniform s_cbranch (isn[r]
    // is a per-wave scalar; no divergence). Number rows issue no VMEM here —
    // R6's dummy-load trick cost ~half the load-path VMEM slots for nothing.
    // Loads stay grouped at the top; 32 resident waves/CU hide the one
    // isnum->branch latency at wave start.
    f32x4 v[RPW][3];
#pragma unroll
    for (int r = 0; r < RPW; ++r) {
        if (!isn[r]) {
            const f32x4* src = reinterpret_cast<const f32x4*>(embeds + (size_t)(base + r) * DDIM);
#pragma unroll
            for (int k = 0; k < 3; ++k) {
                v[r][k] = src[lane + 64 * k];
            }
        }
    }

#pragma unroll
    for (int k = 0; k < 3; ++k) {
        const int d0 = (lane + 64 * k) * 4;
        f32x4 wv[NLIN], b2[NLIN];
#pragma unroll
        for (int n = 0; n < NLIN; ++n) {
            wv[n] = *reinterpret_cast<const f32x4*>(W + n * DDIM + d0);
            const f32x4 bv = *reinterpret_cast<const f32x4*>(bias + n * DDIM + d0);
            b2[n] = bv * LOG2E;   // pre-scale bias into log2 domain
        }
#pragma unroll
        for (int r = 0; r < RPW; ++r) {
            f32x4 o;
            if (isn[r]) {   // wave-uniform: compute only number rows
                f32x4 acc = {0.0f, 0.0f, 0.0f, 0.0f};
#pragma unroll
                for (int n = 0; n < NLIN; ++n) {
                    // sigmoid(f*w+b) = rcp(1 + 2^(-(log2(num)*w + b*log2e)))
                    acc.x += RCP(1.0f + EXP2(-fmaf(g[r], wv[n].x, b2[n].x)));
                    acc.y += RCP(1.0f + EXP2(-fmaf(g[r], wv[n].y, b2[n].y)));
                    acc.z += RCP(1.0f + EXP2(-fmaf(g[r], wv[n].z, b2[n].z)));
                    acc.w += RCP(1.0f + EXP2(-fmaf(g[r], wv[n].w, b2[n].w)));
                }
                o = acc;
            } else {
                o = v[r][k];
            }
            f32x4* dst = reinterpret_cast<f32x4*>(out + (size_t)(base + r) * DDIM);
            // NT store: out is write-once in the timed loop (neutral in R6,
            // kept to preserve L3 for the embeds read stream).
            __builtin_nontemporal_store(o, dst + lane + 64 * k);
        }
    }
}

extern "C" void kernel_launch(void* const* d_in, const int* in_sizes, int n_in,
                              void* d_out, int out_size, void* d_ws, size_t ws_size,
                              hipStream_t stream) {
    const float* embeds  = (const float*)d_in[0];
    const float* numbers = (const float*)d_in[1];
    const int*   isnum   = (const int*)d_in[2];
    const float* W       = (const float*)d_in[3];
    const float* bias    = (const float*)d_in[4];
    float*       out     = (float*)d_out;

    const int rows  = in_sizes[1];                 // B*S = 32768
    const int waves = (rows + RPW - 1) / RPW;      // 8192
    const int grid  = (waves + (BLOCK / 64) - 1) / (BLOCK / 64);  // 2048 blocks

    ScaleNumEmbed_25726854103624_kernel<<<grid, BLOCK, 0, stream>>>(
        embeds, numbers, isnum, W, bias, out, rows);
}